// Round 9
// baseline (229.916 us; speedup 1.0000x reference)
//
#include <hip/hip_runtime.h>

#define NUM_NODES 16384
#define NPG 8
#define NUM_EDGES 14336
#define EPG 7
#define NUM_RELS 64
#define DIM 128
#define BATCH 2048
#define EPS 1e-8f
#define CAP 512

#define GRID 512
#define TPB 256

using f16x8 = __attribute__((ext_vector_type(8))) _Float16;
using f32x4 = __attribute__((ext_vector_type(4))) float;

// ---- ws layout (bytes) ----
#define BAR_OFF 0u
#define CNT_OFF 256u                 // 64 ints
#define EL_OFF  512u                 // elist: 64*512*4   = 131072
#define BH_OFF  131584u              // Bh:    65*16384*2 = 2129920  (rel 64 = root)
#define MSG_OFF 2261504u             // msg_h: 14336*128*2 = 3670016
#define RTP_OFF 5931520u             // rootp: 16384*128*2 = 4194304
#define WS_NEEDED 10125824u

__device__ __forceinline__ void grid_barrier(int* bar, int target) {
    __threadfence();                 // publish this thread's global writes (device scope)
    __syncthreads();
    if (threadIdx.x == 0) {
        __hip_atomic_fetch_add(bar, 1, __ATOMIC_ACQ_REL, __HIP_MEMORY_SCOPE_AGENT);
        while (__hip_atomic_load(bar, __ATOMIC_ACQUIRE, __HIP_MEMORY_SCOPE_AGENT) < target)
            __builtin_amdgcn_s_sleep(2);
    }
    __syncthreads();
}

// ---------------- the single fused kernel ----------------
// Phase A: pack basis/root -> f16 col-major (in-register 8x8 transpose)  |  bucket edges
// Phase B: relation-grouped MFMA GEMM (msg + rootp), fp32 A gathered+cvt in-register
// Phase C: aggregate + relu + pool + cosine (wave per graph)
__global__ __launch_bounds__(TPB, 2) void rgcn_mono_kernel(
    const float* __restrict__ x, const float* __restrict__ basis,
    const float* __restrict__ root, const float* __restrict__ bias,
    const float* __restrict__ target, const int* __restrict__ edge_index,
    const int* __restrict__ edge_type, float* __restrict__ out, char* ws)
{
    int*      bar     = (int*)(ws + BAR_OFF);
    int*      cnt     = (int*)(ws + CNT_OFF);
    int*      elist   = (int*)(ws + EL_OFF);
    _Float16* Bh      = (_Float16*)(ws + BH_OFF);
    _Float16* msg_h   = (_Float16*)(ws + MSG_OFF);
    _Float16* rootp_h = (_Float16*)(ws + RTP_OFF);

    __shared__ _Float16 Bl[DIM * DIM];   // 32 KB (phase B)
    __shared__ int smeta[128];

    const int bid = blockIdx.x;
    const int tid = threadIdx.x;
    const int flat = bid * TPB + tid;    // 0..131071

    // ================= Phase A =================
    // A1: bucket edges by relation (single pass, global atomics; order-independent)
    if (flat < NUM_EDGES) {
        const int rel = edge_type[flat];
        const int pos = __hip_atomic_fetch_add(&cnt[rel], 1, __ATOMIC_RELAXED,
                                               __HIP_MEMORY_SCOPE_AGENT);
        if (pos < CAP) elist[rel * CAP + pos] = flat;
    }
    // A2: pack B fp32 [d][o] -> f16 col-major [o][d], 8x8 in-register transpose
    // 65 matrices x 256 (8x8)-blocks = 16640 tasks
    if (flat < (NUM_RELS + 1) * 256) {
        const int r   = flat >> 8;
        const int blk = flat & 255;
        const int br  = blk >> 4;        // d-block
        const int bc  = blk & 15;        // o-block
        const float* src = ((r < NUM_RELS) ? (basis + ((size_t)r << 14)) : root)
                           + (br * 8) * DIM + bc * 8;
        _Float16 m[8][8];
        #pragma unroll
        for (int u = 0; u < 8; ++u) {
            const float4 a = *(const float4*)(src + u * DIM);
            const float4 b = *(const float4*)(src + u * DIM + 4);
            m[u][0] = (_Float16)a.x; m[u][1] = (_Float16)a.y;
            m[u][2] = (_Float16)a.z; m[u][3] = (_Float16)a.w;
            m[u][4] = (_Float16)b.x; m[u][5] = (_Float16)b.y;
            m[u][6] = (_Float16)b.z; m[u][7] = (_Float16)b.w;
        }
        _Float16* dst = Bh + ((size_t)r << 14) + (bc * 8) * DIM + br * 8;
        #pragma unroll
        for (int c2 = 0; c2 < 8; ++c2) {
            f16x8 v = {m[0][c2], m[1][c2], m[2][c2], m[3][c2],
                       m[4][c2], m[5][c2], m[6][c2], m[7][c2]};
            *(f16x8*)(dst + c2 * DIM) = v;
        }
    }

    grid_barrier(bar, GRID);

    // ================= Phase B: GEMM =================
    // vtiles: 512 edge tiles (rel*8+part, 64 rows) + 256 root tiles.
    // Root tiles go to the statistically-empty part>=4 blocks (cnt mean 224 -> ~3.5 parts full).
    int vts[2]; int nvt = 0;
    vts[nvt++] = bid;
    if ((bid & 7) >= 4) vts[nvt++] = 512 + (bid >> 3) * 4 + (bid & 7) - 4;

    const int lane = tid & 63;
    const int w    = tid >> 6;
    const int l15  = lane & 15;
    const int q    = lane >> 4;

    for (int it = 0; it < nvt; ++it) {
        const int vt = vts[it];
        __syncthreads();                 // LDS/smeta reuse guard (uniform)
        const bool isEdge = vt < 512;
        bool active = true;
        const _Float16* Bg;
        if (isEdge) {
            const int rel  = vt >> 3;
            const int part = vt & 7;
            const int c    = min(cnt[rel], CAP);
            const int row0 = part * 64;
            active = (row0 < c);
            Bg = Bh + ((size_t)rel << 14);
            if (active && tid < 64) {
                const int j = row0 + tid;
                if (j < c) {
                    const int e = elist[rel * CAP + j];
                    smeta[tid] = edge_index[e];      // global src node
                    smeta[64 + tid] = e;
                } else {
                    smeta[tid] = 0;
                    smeta[64 + tid] = -1;
                }
            }
        } else {
            const int row0 = (vt - 512) * 64;
            Bg = Bh + ((size_t)NUM_RELS << 14);
            if (tid < 64) {
                smeta[tid] = row0 + tid;
                smeta[64 + tid] = row0 + tid;
            }
        }
        if (!active) continue;           // block-uniform

        // stage B: 2048 16B-chunks, XOR swizzle (verified R7/R8 layout)
        #pragma unroll
        for (int i = 0; i < 8; ++i) {
            const int c16 = i * 256 + tid;
            const int cs = c16 ^ ((c16 >> 4) & 7);
            *(f16x8*)(&Bl[cs * 8]) = *(const f16x8*)(Bg + c16 * 8);
        }
        __syncthreads();

        // A fragments: gather fp32 x row, convert in-register
        const int src = smeta[w * 16 + l15];
        const float* xrow = x + ((size_t)src << 7) + q * 8;
        f16x8 a[4];
        #pragma unroll
        for (int kb = 0; kb < 4; ++kb) {
            const float4 lo = *(const float4*)(xrow + kb * 32);
            const float4 hi = *(const float4*)(xrow + kb * 32 + 4);
            f16x8 av;
            av[0] = (_Float16)lo.x; av[1] = (_Float16)lo.y;
            av[2] = (_Float16)lo.z; av[3] = (_Float16)lo.w;
            av[4] = (_Float16)hi.x; av[5] = (_Float16)hi.y;
            av[6] = (_Float16)hi.z; av[7] = (_Float16)hi.w;
            a[kb] = av;
        }

        f32x4 acc[8];
        #pragma unroll
        for (int ct = 0; ct < 8; ++ct) acc[ct] = (f32x4){0.f, 0.f, 0.f, 0.f};

        #pragma unroll
        for (int ct = 0; ct < 8; ++ct) {
            const int col = ct * 16 + l15;
            #pragma unroll
            for (int kb = 0; kb < 4; ++kb) {
                const int chunk = col * 16 + kb * 4 + q;
                const int cs = chunk ^ (col & 7);
                const f16x8 bfr = *(const f16x8*)(&Bl[cs * 8]);
                acc[ct] = __builtin_amdgcn_mfma_f32_16x16x32_f16(a[kb], bfr, acc[ct], 0, 0, 0);
            }
        }

        _Float16* outb = isEdge ? msg_h : rootp_h;
        #pragma unroll
        for (int j = 0; j < 4; ++j) {
            const int r = w * 16 + q * 4 + j;
            const int oid = smeta[64 + r];
            if (oid >= 0) {
                #pragma unroll
                for (int ct = 0; ct < 8; ++ct) {
                    outb[((size_t)oid << 7) + ct * 16 + l15] = (_Float16)acc[ct][j];
                }
            }
        }
    }

    grid_barrier(bar, 2 * GRID);

    // ================= Phase C: finalize (wave per graph) =================
    {
        const int g = bid * 4 + w;               // 512*4 = 2048 graphs
        const int d0 = lane * 2;

        const float2 bv = *(const float2*)(bias + d0);
        float accA[NPG], accB[NPG];
        #pragma unroll
        for (int n = 0; n < NPG; ++n) {
            const _Float16* row = rootp_h + ((size_t)(g * NPG + n) << 7) + d0;
            accA[n] = bv.x + (float)row[0];
            accB[n] = bv.y + (float)row[1];
        }

        const int ebase = g * EPG;
        #pragma unroll
        for (int e = 0; e < EPG; ++e) {
            const int ge  = ebase + e;
            const int dst = edge_index[NUM_EDGES + ge] - g * NPG;
            const _Float16* mrow = msg_h + ((size_t)ge << 7) + d0;
            const float m0 = (float)mrow[0];
            const float m1 = (float)mrow[1];
            #pragma unroll
            for (int n = 0; n < NPG; ++n) {
                accA[n] += (n == dst) ? m0 : 0.f;
                accB[n] += (n == dst) ? m1 : 0.f;
            }
        }

        float p0 = 0.f, p1 = 0.f;
        #pragma unroll
        for (int n = 0; n < NPG; ++n) {
            p0 += fmaxf(accA[n], 0.f);
            p1 += fmaxf(accB[n], 0.f);
        }

        const float2 tv = *(const float2*)(target + (size_t)g * DIM + d0);
        float num_p = p0 * tv.x + p1 * tv.y;
        float na_p  = p0 * p0 + p1 * p1;
        float nb_p  = tv.x * tv.x + tv.y * tv.y;

        #pragma unroll
        for (int off = 32; off > 0; off >>= 1) {
            num_p += __shfl_down(num_p, off);
            na_p  += __shfl_down(na_p, off);
            nb_p  += __shfl_down(nb_p, off);
        }
        if (lane == 0) {
            const float na = fmaxf(sqrtf(na_p), EPS);
            const float nb = fmaxf(sqrtf(nb_p), EPS);
            out[g] = num_p / (na * nb);
        }
    }
}

// ---------------- fallback: verified fp32 single-kernel version (52.8 us) ----------------
__global__ __launch_bounds__(128) void rgcn_fused_kernel(
    const float* __restrict__ x, const float* __restrict__ basis,
    const float* __restrict__ root, const float* __restrict__ bias,
    const float* __restrict__ target, const int* __restrict__ edge_index,
    const int* __restrict__ edge_type, float* __restrict__ out)
{
    const int g = blockIdx.x;
    const int o = threadIdx.x;
    __shared__ float xs[NPG][DIM];
    __shared__ float red[6];
    {
        const float4* xg = reinterpret_cast<const float4*>(x + (size_t)g * NPG * DIM);
        float4* xs4 = reinterpret_cast<float4*>(&xs[0][0]);
        xs4[o] = xg[o];
        xs4[o + 128] = xg[o + 128];
    }
    __syncthreads();
    float acc[NPG];
    const float b = bias[o];
    #pragma unroll
    for (int n = 0; n < NPG; ++n) acc[n] = b;
    for (int d4 = 0; d4 < DIM / 4; ++d4) {
        const float r0 = root[(d4 * 4 + 0) * DIM + o];
        const float r1 = root[(d4 * 4 + 1) * DIM + o];
        const float r2 = root[(d4 * 4 + 2) * DIM + o];
        const float r3 = root[(d4 * 4 + 3) * DIM + o];
        #pragma unroll
        for (int n = 0; n < NPG; ++n) {
            const float4 xv = reinterpret_cast<const float4*>(&xs[n][0])[d4];
            acc[n] += xv.x * r0 + xv.y * r1 + xv.z * r2 + xv.w * r3;
        }
    }
    const int ebase = g * EPG;
    for (int e = 0; e < EPG; ++e) {
        const int ge  = ebase + e;
        const int src = edge_index[ge] - g * NPG;
        const int dst = edge_index[NUM_EDGES + ge] - g * NPG;
        const int rel = edge_type[ge];
        const float* __restrict__ B = basis + (size_t)rel * DIM * DIM;
        float m = 0.f;
        for (int d4 = 0; d4 < DIM / 4; ++d4) {
            const float4 xv = reinterpret_cast<const float4*>(&xs[src][0])[d4];
            m += xv.x * B[(d4 * 4 + 0) * DIM + o];
            m += xv.y * B[(d4 * 4 + 1) * DIM + o];
            m += xv.z * B[(d4 * 4 + 2) * DIM + o];
            m += xv.w * B[(d4 * 4 + 3) * DIM + o];
        }
        #pragma unroll
        for (int n = 0; n < NPG; ++n) acc[n] += (n == dst) ? m : 0.f;
    }
    float p = 0.f;
    #pragma unroll
    for (int n = 0; n < NPG; ++n) p += fmaxf(acc[n], 0.f);
    const float t = target[(size_t)g * DIM + o];
    float num_p = p * t, na_p = p * p, nb_p = t * t;
    #pragma unroll
    for (int off = 32; off > 0; off >>= 1) {
        num_p += __shfl_down(num_p, off);
        na_p  += __shfl_down(na_p, off);
        nb_p  += __shfl_down(nb_p, off);
    }
    const int wave = o >> 6, lane = o & 63;
    if (lane == 0) {
        red[wave * 3 + 0] = num_p;
        red[wave * 3 + 1] = na_p;
        red[wave * 3 + 2] = nb_p;
    }
    __syncthreads();
    if (o == 0) {
        const float num = red[0] + red[3];
        const float na  = fmaxf(sqrtf(red[1] + red[4]), EPS);
        const float nb  = fmaxf(sqrtf(red[2] + red[5]), EPS);
        out[g] = num / (na * nb);
    }
}

extern "C" void kernel_launch(void* const* d_in, const int* in_sizes, int n_in,
                              void* d_out, int out_size, void* d_ws, size_t ws_size,
                              hipStream_t stream) {
    const float* x          = (const float*)d_in[0];
    const float* basis      = (const float*)d_in[1];
    const float* root       = (const float*)d_in[2];
    const float* bias       = (const float*)d_in[3];
    const float* target     = (const float*)d_in[4];
    const int*   edge_index = (const int*)d_in[5];
    const int*   edge_type  = (const int*)d_in[6];
    float* out = (float*)d_out;

    if (ws_size < WS_NEEDED) {
        rgcn_fused_kernel<<<BATCH, 128, 0, stream>>>(
            x, basis, root, bias, target, edge_index, edge_type, out);
        return;
    }

    // zero the control region (barrier counter + per-relation counts)
    hipMemsetAsync(d_ws, 0, 512, stream);
    rgcn_mono_kernel<<<GRID, TPB, 0, stream>>>(
        x, basis, root, bias, target, edge_index, edge_type, out, (char*)d_ws);
}

// Round 10
// 102.168 us; speedup vs baseline: 2.2504x; 2.2504x over previous
//
#include <hip/hip_runtime.h>

#define NUM_NODES 16384
#define NPG 8
#define NUM_EDGES 14336
#define EPG 7
#define NUM_RELS 64
#define DIM 128
#define BATCH 2048
#define EPS 1e-8f
#define CAP 512

#define GRID 512
#define TPB 256

using f16x8 = __attribute__((ext_vector_type(8))) _Float16;
using f32x4 = __attribute__((ext_vector_type(4))) float;

// ---- ws layout (bytes) ----
#define BAR_OFF 0u
#define CNT_OFF 256u                 // 64 ints
#define EL_OFF  512u                 // elist: 64*512*4   = 131072
#define BH_OFF  131584u              // Bh:    65*16384*2 = 2129920  (rel 64 = root)
#define MSG_OFF 2261504u             // msg_h: 14336*128*2 = 3670016
#define RTP_OFF 5931520u             // rootp: 16384*128*2 = 4194304
#define WS_NEEDED 10125824u

// Canonical cooperative grid barrier. __syncthreads() drains every wave's
// writes into the XCD cache hierarchy (compiler emits vmcnt(0) before
// s_barrier). Then ONE thread per block does the device-scope publish
// (RELEASE fetch_add -> L2 writeback), polls RELAXED (no cache ops per
// spin), and a single ACQUIRE on exit invalidates stale L1/L2 for the CU.
// R9's bug: threadfence in all 131072 threads + ACQUIRE per poll = 200us
// of coherence-op storms.
__device__ __forceinline__ void grid_barrier(int* bar, int target) {
    __syncthreads();
    if (threadIdx.x == 0) {
        __hip_atomic_fetch_add(bar, 1, __ATOMIC_RELEASE, __HIP_MEMORY_SCOPE_AGENT);
        while (__hip_atomic_load(bar, __ATOMIC_RELAXED, __HIP_MEMORY_SCOPE_AGENT) < target)
            __builtin_amdgcn_s_sleep(8);
        (void)__hip_atomic_load(bar, __ATOMIC_ACQUIRE, __HIP_MEMORY_SCOPE_AGENT);
    }
    __syncthreads();
}

// ---------------- the single fused kernel ----------------
// Phase A: pack basis/root -> f16 col-major (in-register 8x8 transpose) | bucket edges
// Phase B: relation-grouped MFMA GEMM (msg + rootp), fp32 A gathered+cvt in-register
// Phase C: aggregate + relu + pool + cosine (wave per graph)
__global__ __launch_bounds__(TPB, 2) void rgcn_mono_kernel(
    const float* __restrict__ x, const float* __restrict__ basis,
    const float* __restrict__ root, const float* __restrict__ bias,
    const float* __restrict__ target, const int* __restrict__ edge_index,
    const int* __restrict__ edge_type, float* __restrict__ out, char* ws)
{
    int*      bar     = (int*)(ws + BAR_OFF);
    int*      cnt     = (int*)(ws + CNT_OFF);
    int*      elist   = (int*)(ws + EL_OFF);
    _Float16* Bh      = (_Float16*)(ws + BH_OFF);
    _Float16* msg_h   = (_Float16*)(ws + MSG_OFF);
    _Float16* rootp_h = (_Float16*)(ws + RTP_OFF);

    __shared__ _Float16 Bl[DIM * DIM];   // 32 KB (phase B)
    __shared__ int smeta[128];

    const int bid = blockIdx.x;
    const int tid = threadIdx.x;
    const int flat = bid * TPB + tid;    // 0..131071

    // ================= Phase A =================
    // A1: bucket edges by relation (single pass; slot order nondeterministic but
    // every msg/finalize value is slot-independent -> output deterministic)
    if (flat < NUM_EDGES) {
        const int rel = edge_type[flat];
        const int pos = __hip_atomic_fetch_add(&cnt[rel], 1, __ATOMIC_RELAXED,
                                               __HIP_MEMORY_SCOPE_AGENT);
        if (pos < CAP) elist[rel * CAP + pos] = flat;
    }
    // A2: pack B fp32 [d][o] -> f16 col-major [o][d], 8x8 in-register transpose
    if (flat < (NUM_RELS + 1) * 256) {
        const int r   = flat >> 8;
        const int blk = flat & 255;
        const int br  = blk >> 4;        // d-block
        const int bc  = blk & 15;        // o-block
        const float* src = ((r < NUM_RELS) ? (basis + ((size_t)r << 14)) : root)
                           + (br * 8) * DIM + bc * 8;
        _Float16 m[8][8];
        #pragma unroll
        for (int u = 0; u < 8; ++u) {
            const float4 a = *(const float4*)(src + u * DIM);
            const float4 b = *(const float4*)(src + u * DIM + 4);
            m[u][0] = (_Float16)a.x; m[u][1] = (_Float16)a.y;
            m[u][2] = (_Float16)a.z; m[u][3] = (_Float16)a.w;
            m[u][4] = (_Float16)b.x; m[u][5] = (_Float16)b.y;
            m[u][6] = (_Float16)b.z; m[u][7] = (_Float16)b.w;
        }
        _Float16* dst = Bh + ((size_t)r << 14) + (bc * 8) * DIM + br * 8;
        #pragma unroll
        for (int c2 = 0; c2 < 8; ++c2) {
            f16x8 v = {m[0][c2], m[1][c2], m[2][c2], m[3][c2],
                       m[4][c2], m[5][c2], m[6][c2], m[7][c2]};
            *(f16x8*)(dst + c2 * DIM) = v;
        }
    }

    grid_barrier(bar, GRID);

    // ================= Phase B: GEMM =================
    int vts[2]; int nvt = 0;
    vts[nvt++] = bid;
    if ((bid & 7) >= 4) vts[nvt++] = 512 + (bid >> 3) * 4 + (bid & 7) - 4;

    const int lane = tid & 63;
    const int w    = tid >> 6;
    const int l15  = lane & 15;
    const int q    = lane >> 4;

    for (int it = 0; it < nvt; ++it) {
        const int vt = vts[it];
        __syncthreads();                 // LDS/smeta reuse guard (uniform)
        const bool isEdge = vt < 512;
        bool active = true;
        const _Float16* Bg;
        if (isEdge) {
            const int rel  = vt >> 3;
            const int part = vt & 7;
            const int c    = min(cnt[rel], CAP);
            const int row0 = part * 64;
            active = (row0 < c);
            Bg = Bh + ((size_t)rel << 14);
            if (active && tid < 64) {
                const int j = row0 + tid;
                if (j < c) {
                    const int e = elist[rel * CAP + j];
                    smeta[tid] = edge_index[e];      // global src node
                    smeta[64 + tid] = e;
                } else {
                    smeta[tid] = 0;
                    smeta[64 + tid] = -1;
                }
            }
        } else {
            const int row0 = (vt - 512) * 64;
            Bg = Bh + ((size_t)NUM_RELS << 14);
            if (tid < 64) {
                smeta[tid] = row0 + tid;
                smeta[64 + tid] = row0 + tid;
            }
        }
        if (!active) continue;           // block-uniform

        // stage B: 2048 16B-chunks, XOR swizzle (verified R7/R8 layout)
        #pragma unroll
        for (int i = 0; i < 8; ++i) {
            const int c16 = i * 256 + tid;
            const int cs = c16 ^ ((c16 >> 4) & 7);
            *(f16x8*)(&Bl[cs * 8]) = *(const f16x8*)(Bg + c16 * 8);
        }
        __syncthreads();

        // A fragments: gather fp32 x row, convert in-register
        const int src = smeta[w * 16 + l15];
        const float* xrow = x + ((size_t)src << 7) + q * 8;
        f16x8 a[4];
        #pragma unroll
        for (int kb = 0; kb < 4; ++kb) {
            const float4 lo = *(const float4*)(xrow + kb * 32);
            const float4 hi = *(const float4*)(xrow + kb * 32 + 4);
            f16x8 av;
            av[0] = (_Float16)lo.x; av[1] = (_Float16)lo.y;
            av[2] = (_Float16)lo.z; av[3] = (_Float16)lo.w;
            av[4] = (_Float16)hi.x; av[5] = (_Float16)hi.y;
            av[6] = (_Float16)hi.z; av[7] = (_Float16)hi.w;
            a[kb] = av;
        }

        f32x4 acc[8];
        #pragma unroll
        for (int ct = 0; ct < 8; ++ct) acc[ct] = (f32x4){0.f, 0.f, 0.f, 0.f};

        #pragma unroll
        for (int ct = 0; ct < 8; ++ct) {
            const int col = ct * 16 + l15;
            #pragma unroll
            for (int kb = 0; kb < 4; ++kb) {
                const int chunk = col * 16 + kb * 4 + q;
                const int cs = chunk ^ (col & 7);
                const f16x8 bfr = *(const f16x8*)(&Bl[cs * 8]);
                acc[ct] = __builtin_amdgcn_mfma_f32_16x16x32_f16(a[kb], bfr, acc[ct], 0, 0, 0);
            }
        }

        _Float16* outb = isEdge ? msg_h : rootp_h;
        #pragma unroll
        for (int j = 0; j < 4; ++j) {
            const int r = w * 16 + q * 4 + j;
            const int oid = smeta[64 + r];
            if (oid >= 0) {
                #pragma unroll
                for (int ct = 0; ct < 8; ++ct) {
                    outb[((size_t)oid << 7) + ct * 16 + l15] = (_Float16)acc[ct][j];
                }
            }
        }
    }

    grid_barrier(bar, 2 * GRID);

    // ================= Phase C: finalize (wave per graph) =================
    {
        const int g = bid * 4 + w;               // 512*4 = 2048 graphs
        const int d0 = lane * 2;

        const float2 bv = *(const float2*)(bias + d0);
        float accA[NPG], accB[NPG];
        #pragma unroll
        for (int n = 0; n < NPG; ++n) {
            const _Float16* row = rootp_h + ((size_t)(g * NPG + n) << 7) + d0;
            accA[n] = bv.x + (float)row[0];
            accB[n] = bv.y + (float)row[1];
        }

        const int ebase = g * EPG;
        #pragma unroll
        for (int e = 0; e < EPG; ++e) {
            const int ge  = ebase + e;
            const int dst = edge_index[NUM_EDGES + ge] - g * NPG;
            const _Float16* mrow = msg_h + ((size_t)ge << 7) + d0;
            const float m0 = (float)mrow[0];
            const float m1 = (float)mrow[1];
            #pragma unroll
            for (int n = 0; n < NPG; ++n) {
                accA[n] += (n == dst) ? m0 : 0.f;
                accB[n] += (n == dst) ? m1 : 0.f;
            }
        }

        float p0 = 0.f, p1 = 0.f;
        #pragma unroll
        for (int n = 0; n < NPG; ++n) {
            p0 += fmaxf(accA[n], 0.f);
            p1 += fmaxf(accB[n], 0.f);
        }

        const float2 tv = *(const float2*)(target + (size_t)g * DIM + d0);
        float num_p = p0 * tv.x + p1 * tv.y;
        float na_p  = p0 * p0 + p1 * p1;
        float nb_p  = tv.x * tv.x + tv.y * tv.y;

        #pragma unroll
        for (int off = 32; off > 0; off >>= 1) {
            num_p += __shfl_down(num_p, off);
            na_p  += __shfl_down(na_p, off);
            nb_p  += __shfl_down(nb_p, off);
        }
        if (lane == 0) {
            const float na = fmaxf(sqrtf(na_p), EPS);
            const float nb = fmaxf(sqrtf(nb_p), EPS);
            out[g] = num_p / (na * nb);
        }
    }
}

// ---------------- fallback: verified fp32 single-kernel version (52.8 us) ----------------
__global__ __launch_bounds__(128) void rgcn_fused_kernel(
    const float* __restrict__ x, const float* __restrict__ basis,
    const float* __restrict__ root, const float* __restrict__ bias,
    const float* __restrict__ target, const int* __restrict__ edge_index,
    const int* __restrict__ edge_type, float* __restrict__ out)
{
    const int g = blockIdx.x;
    const int o = threadIdx.x;
    __shared__ float xs[NPG][DIM];
    __shared__ float red[6];
    {
        const float4* xg = reinterpret_cast<const float4*>(x + (size_t)g * NPG * DIM);
        float4* xs4 = reinterpret_cast<float4*>(&xs[0][0]);
        xs4[o] = xg[o];
        xs4[o + 128] = xg[o + 128];
    }
    __syncthreads();
    float acc[NPG];
    const float b = bias[o];
    #pragma unroll
    for (int n = 0; n < NPG; ++n) acc[n] = b;
    for (int d4 = 0; d4 < DIM / 4; ++d4) {
        const float r0 = root[(d4 * 4 + 0) * DIM + o];
        const float r1 = root[(d4 * 4 + 1) * DIM + o];
        const float r2 = root[(d4 * 4 + 2) * DIM + o];
        const float r3 = root[(d4 * 4 + 3) * DIM + o];
        #pragma unroll
        for (int n = 0; n < NPG; ++n) {
            const float4 xv = reinterpret_cast<const float4*>(&xs[n][0])[d4];
            acc[n] += xv.x * r0 + xv.y * r1 + xv.z * r2 + xv.w * r3;
        }
    }
    const int ebase = g * EPG;
    for (int e = 0; e < EPG; ++e) {
        const int ge  = ebase + e;
        const int src = edge_index[ge] - g * NPG;
        const int dst = edge_index[NUM_EDGES + ge] - g * NPG;
        const int rel = edge_type[ge];
        const float* __restrict__ B = basis + (size_t)rel * DIM * DIM;
        float m = 0.f;
        for (int d4 = 0; d4 < DIM / 4; ++d4) {
            const float4 xv = reinterpret_cast<const float4*>(&xs[src][0])[d4];
            m += xv.x * B[(d4 * 4 + 0) * DIM + o];
            m += xv.y * B[(d4 * 4 + 1) * DIM + o];
            m += xv.z * B[(d4 * 4 + 2) * DIM + o];
            m += xv.w * B[(d4 * 4 + 3) * DIM + o];
        }
        #pragma unroll
        for (int n = 0; n < NPG; ++n) acc[n] += (n == dst) ? m : 0.f;
    }
    float p = 0.f;
    #pragma unroll
    for (int n = 0; n < NPG; ++n) p += fmaxf(acc[n], 0.f);
    const float t = target[(size_t)g * DIM + o];
    float num_p = p * t, na_p = p * p, nb_p = t * t;
    #pragma unroll
    for (int off = 32; off > 0; off >>= 1) {
        num_p += __shfl_down(num_p, off);
        na_p  += __shfl_down(na_p, off);
        nb_p  += __shfl_down(nb_p, off);
    }
    const int wave = o >> 6, lane = o & 63;
    if (lane == 0) {
        red[wave * 3 + 0] = num_p;
        red[wave * 3 + 1] = na_p;
        red[wave * 3 + 2] = nb_p;
    }
    __syncthreads();
    if (o == 0) {
        const float num = red[0] + red[3];
        const float na  = fmaxf(sqrtf(red[1] + red[4]), EPS);
        const float nb  = fmaxf(sqrtf(red[2] + red[5]), EPS);
        out[g] = num / (na * nb);
    }
}

extern "C" void kernel_launch(void* const* d_in, const int* in_sizes, int n_in,
                              void* d_out, int out_size, void* d_ws, size_t ws_size,
                              hipStream_t stream) {
    const float* x          = (const float*)d_in[0];
    const float* basis      = (const float*)d_in[1];
    const float* root       = (const float*)d_in[2];
    const float* bias       = (const float*)d_in[3];
    const float* target     = (const float*)d_in[4];
    const int*   edge_index = (const int*)d_in[5];
    const int*   edge_type  = (const int*)d_in[6];
    float* out = (float*)d_out;

    if (ws_size < WS_NEEDED) {
        rgcn_fused_kernel<<<BATCH, 128, 0, stream>>>(
            x, basis, root, bias, target, edge_index, edge_type, out);
        return;
    }

    // zero the control region (barrier counter + per-relation counts)
    hipMemsetAsync(d_ws, 0, 512, stream);
    rgcn_mono_kernel<<<GRID, TPB, 0, stream>>>(
        x, basis, root, bias, target, edge_index, edge_type, out, (char*)d_ws);
}

// Round 11
// 49.378 us; speedup vs baseline: 4.6563x; 2.0691x over previous
//
#include <hip/hip_runtime.h>

#define NUM_NODES 16384
#define NPG 8
#define NUM_EDGES 14336
#define EPG 7
#define NUM_RELS 64
#define DIM 128
#define BATCH 2048
#define EPS 1e-8f
#define CAP 512

#define EDGE_BLOCKS 512              // 64 rel x 8 parts x 64 rows
#define ROOT_BLOCKS 256              // 16384 / 64
#define PACK_BLOCKS (NUM_RELS + 1)   // 65 (rel 64 = root)
#define LIST_BLOCKS (NUM_EDGES / 256) // 56
#define PREP_BLOCKS (PACK_BLOCKS + LIST_BLOCKS) // 121

using f16x8 = __attribute__((ext_vector_type(8))) _Float16;
using f32x4 = __attribute__((ext_vector_type(4))) float;

// ---- ws layout (bytes) ----
#define CNT_OFF 0u
#define EL_OFF  256u                 // elist: 64*512*4   = 131072
#define BH_OFF  131328u              // Bh:    65*16384*2 = 2129920
#define MSG_OFF 2261248u             // msg_h: 14336*128*2 = 3670016
#define RTP_OFF 5931264u             // rootp: 16384*128*2 = 4194304
#define WS_NEEDED 10125568u

// ---------------- kernel 1: prep = pack_b (in-register transpose) | bucket edges ----------------
__global__ __launch_bounds__(256) void prep_kernel(
    const float* __restrict__ basis, const float* __restrict__ root,
    const int* __restrict__ edge_type,
    _Float16* __restrict__ Bh, int* __restrict__ cnt, int* __restrict__ elist)
{
    const int bid = blockIdx.x;
    const int tid = threadIdx.x;

    if (bid < PACK_BLOCKS) {
        // pack B fp32 [d][o] -> f16 col-major [o][d]; one 8x8 block per thread,
        // in-register transpose: coalesced float4 reads, coalesced-ish f16x8 writes, no LDS.
        const int r  = bid;
        const int br = tid >> 4;         // d-block
        const int bc = tid & 15;         // o-block
        const float* src = ((r < NUM_RELS) ? (basis + ((size_t)r << 14)) : root)
                           + (br * 8) * DIM + bc * 8;
        _Float16 m[8][8];
        #pragma unroll
        for (int u = 0; u < 8; ++u) {
            const float4 a = *(const float4*)(src + u * DIM);
            const float4 b = *(const float4*)(src + u * DIM + 4);
            m[u][0] = (_Float16)a.x; m[u][1] = (_Float16)a.y;
            m[u][2] = (_Float16)a.z; m[u][3] = (_Float16)a.w;
            m[u][4] = (_Float16)b.x; m[u][5] = (_Float16)b.y;
            m[u][6] = (_Float16)b.z; m[u][7] = (_Float16)b.w;
        }
        _Float16* dst = Bh + ((size_t)r << 14) + (bc * 8) * DIM + br * 8;
        #pragma unroll
        for (int c2 = 0; c2 < 8; ++c2) {
            f16x8 v = {m[0][c2], m[1][c2], m[2][c2], m[3][c2],
                       m[4][c2], m[5][c2], m[6][c2], m[7][c2]};
            *(f16x8*)(dst + c2 * DIM) = v;
        }
    } else {
        // bucket edges: one thread per edge. Slot order is nondeterministic but
        // msg[e] and the finalize sum are slot-independent -> output deterministic.
        const int e = (bid - PACK_BLOCKS) * 256 + tid;   // exactly covers 14336
        const int rel = edge_type[e];
        const int pos = __hip_atomic_fetch_add(&cnt[rel], 1, __ATOMIC_RELAXED,
                                               __HIP_MEMORY_SCOPE_AGENT);
        if (pos < CAP) elist[rel * CAP + pos] = e;
    }
}

// ---------------- kernel 2: MFMA GEMM (edge msgs + root) ----------------
// Verified R8 tile math; A-operand now gathered from fp32 x with in-register cvt
// (verified in R9/R10, absmax identical). Block: 4 waves, one 64-row strip.
// B (128x128 f16 col-major [col][k]) staged in LDS with 16B-chunk XOR swizzle.
__global__ __launch_bounds__(256) void gemm_kernel(
    const float* __restrict__ x, const _Float16* __restrict__ Bh,
    const int* __restrict__ edge_index,
    const int* __restrict__ cnt, const int* __restrict__ elist,
    _Float16* __restrict__ msg_h, _Float16* __restrict__ rootp_h)
{
    __shared__ _Float16 Bl[DIM * DIM];   // 32 KB
    __shared__ int smeta[128];

    const int bid = blockIdx.x;
    const int tid = threadIdx.x;
    const bool isEdge = bid < EDGE_BLOCKS;
    const _Float16* Bg;

    if (isEdge) {
        const int rel  = bid >> 3;
        const int part = bid & 7;
        const int c    = min(cnt[rel], CAP);
        const int row0 = part * 64;
        if (row0 >= c) return;           // block-uniform exit before barrier
        Bg = Bh + ((size_t)rel << 14);
        if (tid < 64) {
            const int j = row0 + tid;
            if (j < c) {
                const int e = elist[rel * CAP + j];
                smeta[tid] = edge_index[e];      // global src node
                smeta[64 + tid] = e;
            } else {
                smeta[tid] = 0;
                smeta[64 + tid] = -1;
            }
        }
    } else {
        const int row0 = (bid - EDGE_BLOCKS) * 64;
        Bg = Bh + ((size_t)NUM_RELS << 14);
        if (tid < 64) {
            smeta[tid] = row0 + tid;
            smeta[64 + tid] = row0 + tid;
        }
    }

    // stage B: 2048 16B-chunks, XOR swizzle
    #pragma unroll
    for (int i = 0; i < 8; ++i) {
        const int c16 = i * 256 + tid;
        const int cs = c16 ^ ((c16 >> 4) & 7);
        *(f16x8*)(&Bl[cs * 8]) = *(const f16x8*)(Bg + c16 * 8);
    }
    __syncthreads();

    const int lane = tid & 63;
    const int w    = tid >> 6;
    const int l15  = lane & 15;
    const int q    = lane >> 4;

    // A fragments: gather fp32 x row, convert in-register
    const int src = smeta[w * 16 + l15];
    const float* xrow = x + ((size_t)src << 7) + q * 8;
    f16x8 a[4];
    #pragma unroll
    for (int kb = 0; kb < 4; ++kb) {
        const float4 lo = *(const float4*)(xrow + kb * 32);
        const float4 hi = *(const float4*)(xrow + kb * 32 + 4);
        f16x8 av;
        av[0] = (_Float16)lo.x; av[1] = (_Float16)lo.y;
        av[2] = (_Float16)lo.z; av[3] = (_Float16)lo.w;
        av[4] = (_Float16)hi.x; av[5] = (_Float16)hi.y;
        av[6] = (_Float16)hi.z; av[7] = (_Float16)hi.w;
        a[kb] = av;
    }

    f32x4 acc[8];
    #pragma unroll
    for (int ct = 0; ct < 8; ++ct) acc[ct] = (f32x4){0.f, 0.f, 0.f, 0.f};

    #pragma unroll
    for (int ct = 0; ct < 8; ++ct) {
        const int col = ct * 16 + l15;
        #pragma unroll
        for (int kb = 0; kb < 4; ++kb) {
            const int chunk = col * 16 + kb * 4 + q;
            const int cs = chunk ^ (col & 7);
            const f16x8 bfr = *(const f16x8*)(&Bl[cs * 8]);
            acc[ct] = __builtin_amdgcn_mfma_f32_16x16x32_f16(a[kb], bfr, acc[ct], 0, 0, 0);
        }
    }

    _Float16* outb = isEdge ? msg_h : rootp_h;
    #pragma unroll
    for (int j = 0; j < 4; ++j) {
        const int r = w * 16 + q * 4 + j;
        const int oid = smeta[64 + r];
        if (oid >= 0) {
            #pragma unroll
            for (int ct = 0; ct < 8; ++ct) {
                outb[((size_t)oid << 7) + ct * 16 + l15] = (_Float16)acc[ct][j];
            }
        }
    }
}

// ---------------- kernel 3: finalize, wave-per-graph (verified R8) ----------------
__global__ __launch_bounds__(256) void finalize_kernel(
    const _Float16* __restrict__ rootp_h, const _Float16* __restrict__ msg_h,
    const float* __restrict__ bias, const float* __restrict__ target,
    const int* __restrict__ edge_index, float* __restrict__ out)
{
    const int g = blockIdx.x * 4 + (threadIdx.x >> 6);
    const int l = threadIdx.x & 63;
    const int d0 = l * 2;

    const float2 bv = *(const float2*)(bias + d0);
    float accA[NPG], accB[NPG];
    #pragma unroll
    for (int n = 0; n < NPG; ++n) {
        const _Float16* row = rootp_h + ((size_t)(g * NPG + n) << 7) + d0;
        accA[n] = bv.x + (float)row[0];
        accB[n] = bv.y + (float)row[1];
    }

    const int ebase = g * EPG;
    #pragma unroll
    for (int e = 0; e < EPG; ++e) {
        const int ge  = ebase + e;
        const int dst = edge_index[NUM_EDGES + ge] - g * NPG;
        const _Float16* mrow = msg_h + ((size_t)ge << 7) + d0;
        const float m0 = (float)mrow[0];
        const float m1 = (float)mrow[1];
        #pragma unroll
        for (int n = 0; n < NPG; ++n) {
            accA[n] += (n == dst) ? m0 : 0.f;
            accB[n] += (n == dst) ? m1 : 0.f;
        }
    }

    float p0 = 0.f, p1 = 0.f;
    #pragma unroll
    for (int n = 0; n < NPG; ++n) {
        p0 += fmaxf(accA[n], 0.f);
        p1 += fmaxf(accB[n], 0.f);
    }

    const float2 tv = *(const float2*)(target + (size_t)g * DIM + d0);
    float num_p = p0 * tv.x + p1 * tv.y;
    float na_p  = p0 * p0 + p1 * p1;
    float nb_p  = tv.x * tv.x + tv.y * tv.y;

    #pragma unroll
    for (int off = 32; off > 0; off >>= 1) {
        num_p += __shfl_down(num_p, off);
        na_p  += __shfl_down(na_p, off);
        nb_p  += __shfl_down(nb_p, off);
    }
    if (l == 0) {
        const float na = fmaxf(sqrtf(na_p), EPS);
        const float nb = fmaxf(sqrtf(nb_p), EPS);
        out[g] = num_p / (na * nb);
    }
}

// ---------------- fallback: verified fp32 single-kernel version (52.8 us) ----------------
__global__ __launch_bounds__(128) void rgcn_fused_kernel(
    const float* __restrict__ x, const float* __restrict__ basis,
    const float* __restrict__ root, const float* __restrict__ bias,
    const float* __restrict__ target, const int* __restrict__ edge_index,
    const int* __restrict__ edge_type, float* __restrict__ out)
{
    const int g = blockIdx.x;
    const int o = threadIdx.x;
    __shared__ float xs[NPG][DIM];
    __shared__ float red[6];
    {
        const float4* xg = reinterpret_cast<const float4*>(x + (size_t)g * NPG * DIM);
        float4* xs4 = reinterpret_cast<float4*>(&xs[0][0]);
        xs4[o] = xg[o];
        xs4[o + 128] = xg[o + 128];
    }
    __syncthreads();
    float acc[NPG];
    const float b = bias[o];
    #pragma unroll
    for (int n = 0; n < NPG; ++n) acc[n] = b;
    for (int d4 = 0; d4 < DIM / 4; ++d4) {
        const float r0 = root[(d4 * 4 + 0) * DIM + o];
        const float r1 = root[(d4 * 4 + 1) * DIM + o];
        const float r2 = root[(d4 * 4 + 2) * DIM + o];
        const float r3 = root[(d4 * 4 + 3) * DIM + o];
        #pragma unroll
        for (int n = 0; n < NPG; ++n) {
            const float4 xv = reinterpret_cast<const float4*>(&xs[n][0])[d4];
            acc[n] += xv.x * r0 + xv.y * r1 + xv.z * r2 + xv.w * r3;
        }
    }
    const int ebase = g * EPG;
    for (int e = 0; e < EPG; ++e) {
        const int ge  = ebase + e;
        const int src = edge_index[ge] - g * NPG;
        const int dst = edge_index[NUM_EDGES + ge] - g * NPG;
        const int rel = edge_type[ge];
        const float* __restrict__ B = basis + (size_t)rel * DIM * DIM;
        float m = 0.f;
        for (int d4 = 0; d4 < DIM / 4; ++d4) {
            const float4 xv = reinterpret_cast<const float4*>(&xs[src][0])[d4];
            m += xv.x * B[(d4 * 4 + 0) * DIM + o];
            m += xv.y * B[(d4 * 4 + 1) * DIM + o];
            m += xv.z * B[(d4 * 4 + 2) * DIM + o];
            m += xv.w * B[(d4 * 4 + 3) * DIM + o];
        }
        #pragma unroll
        for (int n = 0; n < NPG; ++n) acc[n] += (n == dst) ? m : 0.f;
    }
    float p = 0.f;
    #pragma unroll
    for (int n = 0; n < NPG; ++n) p += fmaxf(acc[n], 0.f);
    const float t = target[(size_t)g * DIM + o];
    float num_p = p * t, na_p = p * p, nb_p = t * t;
    #pragma unroll
    for (int off = 32; off > 0; off >>= 1) {
        num_p += __shfl_down(num_p, off);
        na_p  += __shfl_down(na_p, off);
        nb_p  += __shfl_down(nb_p, off);
    }
    const int wave = o >> 6, lane = o & 63;
    if (lane == 0) {
        red[wave * 3 + 0] = num_p;
        red[wave * 3 + 1] = na_p;
        red[wave * 3 + 2] = nb_p;
    }
    __syncthreads();
    if (o == 0) {
        const float num = red[0] + red[3];
        const float na  = fmaxf(sqrtf(red[1] + red[4]), EPS);
        const float nb  = fmaxf(sqrtf(red[2] + red[5]), EPS);
        out[g] = num / (na * nb);
    }
}

extern "C" void kernel_launch(void* const* d_in, const int* in_sizes, int n_in,
                              void* d_out, int out_size, void* d_ws, size_t ws_size,
                              hipStream_t stream) {
    const float* x          = (const float*)d_in[0];
    const float* basis      = (const float*)d_in[1];
    const float* root       = (const float*)d_in[2];
    const float* bias       = (const float*)d_in[3];
    const float* target     = (const float*)d_in[4];
    const int*   edge_index = (const int*)d_in[5];
    const int*   edge_type  = (const int*)d_in[6];
    float* out = (float*)d_out;

    if (ws_size < WS_NEEDED) {
        rgcn_fused_kernel<<<BATCH, 128, 0, stream>>>(
            x, basis, root, bias, target, edge_index, edge_type, out);
        return;
    }

    char* ws = (char*)d_ws;
    int*      cnt     = (int*)(ws + CNT_OFF);
    int*      elist   = (int*)(ws + EL_OFF);
    _Float16* Bh      = (_Float16*)(ws + BH_OFF);
    _Float16* msg_h   = (_Float16*)(ws + MSG_OFF);
    _Float16* rootp_h = (_Float16*)(ws + RTP_OFF);

    hipMemsetAsync(cnt, 0, 256, stream);   // re-zero per call (replay-safe)
    prep_kernel<<<PREP_BLOCKS, 256, 0, stream>>>(basis, root, edge_type, Bh, cnt, elist);
    gemm_kernel<<<EDGE_BLOCKS + ROOT_BLOCKS, 256, 0, stream>>>(
        x, Bh, edge_index, cnt, elist, msg_h, rootp_h);
    finalize_kernel<<<BATCH / 4, 256, 0, stream>>>(
        rootp_h, msg_h, bias, target, edge_index, out);
}

// Round 12
// 36.666 us; speedup vs baseline: 6.2706x; 1.3467x over previous
//
#include <hip/hip_runtime.h>

#define NUM_NODES 16384
#define NPG 8
#define NUM_EDGES 14336
#define EPG 7
#define NUM_RELS 64
#define DIM 128
#define BATCH 2048
#define EPS 1e-8f
#define CAP 512

#define EDGE_BLOCKS 512              // 64 rel x 8 parts x 64 rows
#define ROOT_BLOCKS 256              // 16384 / 64
#define PACK_BLOCKS (NUM_RELS + 1)   // 65 (rel 64 = root)
#define PREP_BLOCKS (PACK_BLOCKS + NUM_RELS)   // 129

using f16x8 = __attribute__((ext_vector_type(8))) _Float16;
using f32x4 = __attribute__((ext_vector_type(4))) float;

// ---- ws layout (bytes) ----
#define CNT_OFF 0u
#define EL_OFF  256u                 // elist: 64*512*4   = 131072
#define BH_OFF  131328u              // Bh:    65*16384*2 = 2129920
#define MSG_OFF 2261248u             // msg_h: 14336*128*2 = 3670016
#define RTP_OFF 5931264u             // rootp: 16384*128*2 = 4194304
#define WS_NEEDED 10125568u

// ---------------- kernel 1: prep = pack_b (in-register transpose) | bucket edges ----------------
// NO global memset dependency: bucket block r counts in __shared__ and WRITES cnt[r].
// (R11 lesson: a 256B hipMemsetAsync node in the graph costs ~10-40us on this machine.)
__global__ __launch_bounds__(256) void prep_kernel(
    const float* __restrict__ basis, const float* __restrict__ root,
    const int* __restrict__ edge_type,
    _Float16* __restrict__ Bh, int* __restrict__ cnt, int* __restrict__ elist)
{
    __shared__ int lcnt;
    const int bid = blockIdx.x;
    const int tid = threadIdx.x;

    if (bid < PACK_BLOCKS) {
        // pack B fp32 [d][o] -> f16 col-major [o][d]; one 8x8 block per thread,
        // in-register transpose: coalesced float4 reads, no LDS, no conflicts.
        const int r  = bid;
        const int br = tid >> 4;         // d-block
        const int bc = tid & 15;         // o-block
        const float* src = ((r < NUM_RELS) ? (basis + ((size_t)r << 14)) : root)
                           + (br * 8) * DIM + bc * 8;
        _Float16 m[8][8];
        #pragma unroll
        for (int u = 0; u < 8; ++u) {
            const float4 a = *(const float4*)(src + u * DIM);
            const float4 b = *(const float4*)(src + u * DIM + 4);
            m[u][0] = (_Float16)a.x; m[u][1] = (_Float16)a.y;
            m[u][2] = (_Float16)a.z; m[u][3] = (_Float16)a.w;
            m[u][4] = (_Float16)b.x; m[u][5] = (_Float16)b.y;
            m[u][6] = (_Float16)b.z; m[u][7] = (_Float16)b.w;
        }
        _Float16* dst = Bh + ((size_t)r << 14) + (bc * 8) * DIM + br * 8;
        #pragma unroll
        for (int c2 = 0; c2 < 8; ++c2) {
            f16x8 v = {m[0][c2], m[1][c2], m[2][c2], m[3][c2],
                       m[4][c2], m[5][c2], m[6][c2], m[7][c2]};
            *(f16x8*)(dst + c2 * DIM) = v;
        }
    } else {
        // bucket edges for relation r (R8-verified): LDS counter, write-not-accumulate cnt.
        // Slot order nondeterministic but msg[e]/finalize are slot-independent -> deterministic output.
        const int r = bid - PACK_BLOCKS;
        if (tid == 0) lcnt = 0;
        __syncthreads();
        for (int e = tid; e < NUM_EDGES; e += 256) {
            if (edge_type[e] == r) {
                const int p = atomicAdd(&lcnt, 1);
                if (p < CAP) elist[r * CAP + p] = e;
            }
        }
        __syncthreads();
        if (tid == 0) cnt[r] = min(lcnt, CAP);
    }
}

// ---------------- kernel 2: MFMA GEMM (edge msgs + root) ----------------
// Verified R8 tile math; A gathered from fp32 x, cvt in-register (verified R9-R11,
// absmax identical). Block: 4 waves, one 64-row strip. B (128x128 f16 col-major
// [col][k]) staged in LDS with 16B-chunk XOR swizzle.
__global__ __launch_bounds__(256) void gemm_kernel(
    const float* __restrict__ x, const _Float16* __restrict__ Bh,
    const int* __restrict__ edge_index,
    const int* __restrict__ cnt, const int* __restrict__ elist,
    _Float16* __restrict__ msg_h, _Float16* __restrict__ rootp_h)
{
    __shared__ _Float16 Bl[DIM * DIM];   // 32 KB
    __shared__ int smeta[128];

    const int bid = blockIdx.x;
    const int tid = threadIdx.x;
    const bool isEdge = bid < EDGE_BLOCKS;
    const _Float16* Bg;

    if (isEdge) {
        const int rel  = bid >> 3;
        const int part = bid & 7;
        const int c    = min(cnt[rel], CAP);
        const int row0 = part * 64;
        if (row0 >= c) return;           // block-uniform exit before barrier
        Bg = Bh + ((size_t)rel << 14);
        if (tid < 64) {
            const int j = row0 + tid;
            if (j < c) {
                const int e = elist[rel * CAP + j];
                smeta[tid] = edge_index[e];      // global src node
                smeta[64 + tid] = e;
            } else {
                smeta[tid] = 0;
                smeta[64 + tid] = -1;
            }
        }
    } else {
        const int row0 = (bid - EDGE_BLOCKS) * 64;
        Bg = Bh + ((size_t)NUM_RELS << 14);
        if (tid < 64) {
            smeta[tid] = row0 + tid;
            smeta[64 + tid] = row0 + tid;
        }
    }

    // stage B: 2048 16B-chunks, XOR swizzle
    #pragma unroll
    for (int i = 0; i < 8; ++i) {
        const int c16 = i * 256 + tid;
        const int cs = c16 ^ ((c16 >> 4) & 7);
        *(f16x8*)(&Bl[cs * 8]) = *(const f16x8*)(Bg + c16 * 8);
    }
    __syncthreads();

    const int lane = tid & 63;
    const int w    = tid >> 6;
    const int l15  = lane & 15;
    const int q    = lane >> 4;

    // A fragments: gather fp32 x row, convert in-register
    const int src = smeta[w * 16 + l15];
    const float* xrow = x + ((size_t)src << 7) + q * 8;
    f16x8 a[4];
    #pragma unroll
    for (int kb = 0; kb < 4; ++kb) {
        const float4 lo = *(const float4*)(xrow + kb * 32);
        const float4 hi = *(const float4*)(xrow + kb * 32 + 4);
        f16x8 av;
        av[0] = (_Float16)lo.x; av[1] = (_Float16)lo.y;
        av[2] = (_Float16)lo.z; av[3] = (_Float16)lo.w;
        av[4] = (_Float16)hi.x; av[5] = (_Float16)hi.y;
        av[6] = (_Float16)hi.z; av[7] = (_Float16)hi.w;
        a[kb] = av;
    }

    f32x4 acc[8];
    #pragma unroll
    for (int ct = 0; ct < 8; ++ct) acc[ct] = (f32x4){0.f, 0.f, 0.f, 0.f};

    #pragma unroll
    for (int ct = 0; ct < 8; ++ct) {
        const int col = ct * 16 + l15;
        #pragma unroll
        for (int kb = 0; kb < 4; ++kb) {
            const int chunk = col * 16 + kb * 4 + q;
            const int cs = chunk ^ (col & 7);
            const f16x8 bfr = *(const f16x8*)(&Bl[cs * 8]);
            acc[ct] = __builtin_amdgcn_mfma_f32_16x16x32_f16(a[kb], bfr, acc[ct], 0, 0, 0);
        }
    }

    _Float16* outb = isEdge ? msg_h : rootp_h;
    #pragma unroll
    for (int j = 0; j < 4; ++j) {
        const int r = w * 16 + q * 4 + j;
        const int oid = smeta[64 + r];
        if (oid >= 0) {
            #pragma unroll
            for (int ct = 0; ct < 8; ++ct) {
                outb[((size_t)oid << 7) + ct * 16 + l15] = (_Float16)acc[ct][j];
            }
        }
    }
}

// ---------------- kernel 3: finalize, wave-per-graph (verified R8) ----------------
__global__ __launch_bounds__(256) void finalize_kernel(
    const _Float16* __restrict__ rootp_h, const _Float16* __restrict__ msg_h,
    const float* __restrict__ bias, const float* __restrict__ target,
    const int* __restrict__ edge_index, float* __restrict__ out)
{
    const int g = blockIdx.x * 4 + (threadIdx.x >> 6);
    const int l = threadIdx.x & 63;
    const int d0 = l * 2;

    const float2 bv = *(const float2*)(bias + d0);
    float accA[NPG], accB[NPG];
    #pragma unroll
    for (int n = 0; n < NPG; ++n) {
        const _Float16* row = rootp_h + ((size_t)(g * NPG + n) << 7) + d0;
        accA[n] = bv.x + (float)row[0];
        accB[n] = bv.y + (float)row[1];
    }

    const int ebase = g * EPG;
    #pragma unroll
    for (int e = 0; e < EPG; ++e) {
        const int ge  = ebase + e;
        const int dst = edge_index[NUM_EDGES + ge] - g * NPG;
        const _Float16* mrow = msg_h + ((size_t)ge << 7) + d0;
        const float m0 = (float)mrow[0];
        const float m1 = (float)mrow[1];
        #pragma unroll
        for (int n = 0; n < NPG; ++n) {
            accA[n] += (n == dst) ? m0 : 0.f;
            accB[n] += (n == dst) ? m1 : 0.f;
        }
    }

    float p0 = 0.f, p1 = 0.f;
    #pragma unroll
    for (int n = 0; n < NPG; ++n) {
        p0 += fmaxf(accA[n], 0.f);
        p1 += fmaxf(accB[n], 0.f);
    }

    const float2 tv = *(const float2*)(target + (size_t)g * DIM + d0);
    float num_p = p0 * tv.x + p1 * tv.y;
    float na_p  = p0 * p0 + p1 * p1;
    float nb_p  = tv.x * tv.x + tv.y * tv.y;

    #pragma unroll
    for (int off = 32; off > 0; off >>= 1) {
        num_p += __shfl_down(num_p, off);
        na_p  += __shfl_down(na_p, off);
        nb_p  += __shfl_down(nb_p, off);
    }
    if (l == 0) {
        const float na = fmaxf(sqrtf(na_p), EPS);
        const float nb = fmaxf(sqrtf(nb_p), EPS);
        out[g] = num_p / (na * nb);
    }
}

// ---------------- fallback: verified fp32 single-kernel version (52.8 us) ----------------
__global__ __launch_bounds__(128) void rgcn_fused_kernel(
    const float* __restrict__ x, const float* __restrict__ basis,
    const float* __restrict__ root, const float* __restrict__ bias,
    const float* __restrict__ target, const int* __restrict__ edge_index,
    const int* __restrict__ edge_type, float* __restrict__ out)
{
    const int g = blockIdx.x;
    const int o = threadIdx.x;
    __shared__ float xs[NPG][DIM];
    __shared__ float red[6];
    {
        const float4* xg = reinterpret_cast<const float4*>(x + (size_t)g * NPG * DIM);
        float4* xs4 = reinterpret_cast<float4*>(&xs[0][0]);
        xs4[o] = xg[o];
        xs4[o + 128] = xg[o + 128];
    }
    __syncthreads();
    float acc[NPG];
    const float b = bias[o];
    #pragma unroll
    for (int n = 0; n < NPG; ++n) acc[n] = b;
    for (int d4 = 0; d4 < DIM / 4; ++d4) {
        const float r0 = root[(d4 * 4 + 0) * DIM + o];
        const float r1 = root[(d4 * 4 + 1) * DIM + o];
        const float r2 = root[(d4 * 4 + 2) * DIM + o];
        const float r3 = root[(d4 * 4 + 3) * DIM + o];
        #pragma unroll
        for (int n = 0; n < NPG; ++n) {
            const float4 xv = reinterpret_cast<const float4*>(&xs[n][0])[d4];
            acc[n] += xv.x * r0 + xv.y * r1 + xv.z * r2 + xv.w * r3;
        }
    }
    const int ebase = g * EPG;
    for (int e = 0; e < EPG; ++e) {
        const int ge  = ebase + e;
        const int src = edge_index[ge] - g * NPG;
        const int dst = edge_index[NUM_EDGES + ge] - g * NPG;
        const int rel = edge_type[ge];
        const float* __restrict__ B = basis + (size_t)rel * DIM * DIM;
        float m = 0.f;
        for (int d4 = 0; d4 < DIM / 4; ++d4) {
            const float4 xv = reinterpret_cast<const float4*>(&xs[src][0])[d4];
            m += xv.x * B[(d4 * 4 + 0) * DIM + o];
            m += xv.y * B[(d4 * 4 + 1) * DIM + o];
            m += xv.z * B[(d4 * 4 + 2) * DIM + o];
            m += xv.w * B[(d4 * 4 + 3) * DIM + o];
        }
        #pragma unroll
        for (int n = 0; n < NPG; ++n) acc[n] += (n == dst) ? m : 0.f;
    }
    float p = 0.f;
    #pragma unroll
    for (int n = 0; n < NPG; ++n) p += fmaxf(acc[n], 0.f);
    const float t = target[(size_t)g * DIM + o];
    float num_p = p * t, na_p = p * p, nb_p = t * t;
    #pragma unroll
    for (int off = 32; off > 0; off >>= 1) {
        num_p += __shfl_down(num_p, off);
        na_p  += __shfl_down(na_p, off);
        nb_p  += __shfl_down(nb_p, off);
    }
    const int wave = o >> 6, lane = o & 63;
    if (lane == 0) {
        red[wave * 3 + 0] = num_p;
        red[wave * 3 + 1] = na_p;
        red[wave * 3 + 2] = nb_p;
    }
    __syncthreads();
    if (o == 0) {
        const float num = red[0] + red[3];
        const float na  = fmaxf(sqrtf(red[1] + red[4]), EPS);
        const float nb  = fmaxf(sqrtf(red[2] + red[5]), EPS);
        out[g] = num / (na * nb);
    }
}

extern "C" void kernel_launch(void* const* d_in, const int* in_sizes, int n_in,
                              void* d_out, int out_size, void* d_ws, size_t ws_size,
                              hipStream_t stream) {
    const float* x          = (const float*)d_in[0];
    const float* basis      = (const float*)d_in[1];
    const float* root       = (const float*)d_in[2];
    const float* bias       = (const float*)d_in[3];
    const float* target     = (const float*)d_in[4];
    const int*   edge_index = (const int*)d_in[5];
    const int*   edge_type  = (const int*)d_in[6];
    float* out = (float*)d_out;

    if (ws_size < WS_NEEDED) {
        rgcn_fused_kernel<<<BATCH, 128, 0, stream>>>(
            x, basis, root, bias, target, edge_index, edge_type, out);
        return;
    }

    char* ws = (char*)d_ws;
    int*      cnt     = (int*)(ws + CNT_OFF);
    int*      elist   = (int*)(ws + EL_OFF);
    _Float16* Bh      = (_Float16*)(ws + BH_OFF);
    _Float16* msg_h   = (_Float16*)(ws + MSG_OFF);
    _Float16* rootp_h = (_Float16*)(ws + RTP_OFF);

    prep_kernel<<<PREP_BLOCKS, 256, 0, stream>>>(basis, root, edge_type, Bh, cnt, elist);
    gemm_kernel<<<EDGE_BLOCKS + ROOT_BLOCKS, 256, 0, stream>>>(
        x, Bh, edge_index, cnt, elist, msg_h, rootp_h);
    finalize_kernel<<<BATCH / 4, 256, 0, stream>>>(
        rootp_h, msg_h, bias, target, edge_index, out);
}

// Round 13
// 23.357 us; speedup vs baseline: 9.8435x; 1.5698x over previous
//
#include <hip/hip_runtime.h>

#define NUM_NODES 16384
#define NPG 8
#define NUM_EDGES 14336
#define EPG 7
#define NUM_RELS 64
#define DIM 128
#define BATCH 2048
#define EPS 1e-8f

#define SEG 1792                     // NUM_EDGES / 8 segments
#define EDGE_BLOCKS 512              // 64 rel x 8 segments, <=64 edges each (avg 28)
#define ROOT_BLOCKS 256              // 16384 / 64

using f16x8 = __attribute__((ext_vector_type(8))) _Float16;
using f32x4 = __attribute__((ext_vector_type(4))) float;

// ---- ws layout (bytes) ----
#define MSG_OFF 0u                   // msg_h: 14336*128*2 = 3670016
#define RTP_OFF 3670016u             // rootp: 16384*128*2 = 4194304
#define WS_NEEDED 7864320u

// ---------------- kernel 1: fused bucket + pack + MFMA GEMM ----------------
// Edge block (rel=bid>>3, part=bid&7): ballot-bucket its own edge segment
// (deterministic, no atomics), stage B[rel] fp32->f16 transposed into LDS,
// 64-row MFMA strip. Root block: rows row0..row0+63 with root matrix.
// LDS layout: 16B chunks, chunk = col*16 + k16; swizzle
//   cs = chunk ^ (col&7) ^ ((col>>3)&7)
// -> bank-conflict-free on BOTH the transpose stores (lanes vary bc=col>>3)
//    and the fragment reads (lanes vary col). Bank period = 8 chunks = 128B.
__global__ __launch_bounds__(256) void gemm2_kernel(
    const float* __restrict__ x, const float* __restrict__ basis,
    const float* __restrict__ root, const int* __restrict__ edge_index,
    const int* __restrict__ edge_type,
    _Float16* __restrict__ msg_h, _Float16* __restrict__ rootp_h)
{
    __shared__ _Float16 Bl[DIM * DIM];   // 32 KB
    __shared__ int smeta[128];           // [0:64) src node, [64:128) out row id (-1 = skip)
    __shared__ int wcnt[4];

    const int bid = blockIdx.x;
    const int tid = threadIdx.x;
    const int lane = tid & 63;
    const int w    = tid >> 6;
    const bool isEdge = bid < EDGE_BLOCKS;

    const float* Bsrc;

    if (isEdge) {
        const int rel  = bid >> 3;
        const int part = bid & 7;
        Bsrc = basis + ((size_t)rel << 14);

        if (tid < 64) { smeta[tid] = 0; smeta[64 + tid] = -1; }
        __syncthreads();

        // ballot-bucket: ordered prefix over this block's 1792-edge segment
        const int seg0 = part * SEG;
        int run = 0;
        for (int it = 0; it < 7; ++it) {
            const int e = seg0 + it * 256 + tid;
            const bool match = (edge_type[e] == rel);
            const unsigned long long mb = __ballot(match);
            if (lane == 0) wcnt[w] = (int)__popcll(mb);
            __syncthreads();
            int pre = run;
            #pragma unroll
            for (int w2 = 0; w2 < 4; ++w2) if (w2 < w) pre += wcnt[w2];
            const int tot = wcnt[0] + wcnt[1] + wcnt[2] + wcnt[3];
            if (match) {
                const int ord = pre + (int)__popcll(mb & ((1ull << lane) - 1ull));
                if (ord < 64) {
                    smeta[ord] = edge_index[e];      // global src node
                    smeta[64 + ord] = e;             // msg row id
                }
            }
            run += tot;
            __syncthreads();
        }
        if (run == 0) return;            // block-uniform
    } else {
        const int row0 = (bid - EDGE_BLOCKS) * 64;
        Bsrc = root;
        if (tid < 64) {
            smeta[tid] = row0 + tid;
            smeta[64 + tid] = row0 + tid;
        }
    }

    // ---- stage B: fp32 [d][o] -> LDS f16 [col][k], 8x8 in-register transpose ----
    {
        const int br = tid >> 4;         // d-block (k16 = br)
        const int bc = tid & 15;         // o-block
        const float* src = Bsrc + (br * 8) * DIM + bc * 8;
        _Float16 m[8][8];
        #pragma unroll
        for (int u = 0; u < 8; ++u) {
            const float4 a = *(const float4*)(src + u * DIM);
            const float4 b = *(const float4*)(src + u * DIM + 4);
            m[u][0] = (_Float16)a.x; m[u][1] = (_Float16)a.y;
            m[u][2] = (_Float16)a.z; m[u][3] = (_Float16)a.w;
            m[u][4] = (_Float16)b.x; m[u][5] = (_Float16)b.y;
            m[u][6] = (_Float16)b.z; m[u][7] = (_Float16)b.w;
        }
        #pragma unroll
        for (int c2 = 0; c2 < 8; ++c2) {
            const int col = bc * 8 + c2;
            const int chunk = col * 16 + br;
            const int cs = chunk ^ (c2 & 7) ^ (bc & 7);   // == chunk^(col&7)^((col>>3)&7)
            f16x8 v = {m[0][c2], m[1][c2], m[2][c2], m[3][c2],
                       m[4][c2], m[5][c2], m[6][c2], m[7][c2]};
            *(f16x8*)(&Bl[cs * 8]) = v;
        }
    }
    __syncthreads();

    const int l15 = lane & 15;
    const int q   = lane >> 4;

    // A fragments: gather fp32 x row, convert in-register (verified R9-R12)
    const int src = smeta[w * 16 + l15];
    const float* xrow = x + ((size_t)src << 7) + q * 8;
    f16x8 a[4];
    #pragma unroll
    for (int kb = 0; kb < 4; ++kb) {
        const float4 lo = *(const float4*)(xrow + kb * 32);
        const float4 hi = *(const float4*)(xrow + kb * 32 + 4);
        f16x8 av;
        av[0] = (_Float16)lo.x; av[1] = (_Float16)lo.y;
        av[2] = (_Float16)lo.z; av[3] = (_Float16)lo.w;
        av[4] = (_Float16)hi.x; av[5] = (_Float16)hi.y;
        av[6] = (_Float16)hi.z; av[7] = (_Float16)hi.w;
        a[kb] = av;
    }

    f32x4 acc[8];
    #pragma unroll
    for (int ct = 0; ct < 8; ++ct) acc[ct] = (f32x4){0.f, 0.f, 0.f, 0.f};

    #pragma unroll
    for (int ct = 0; ct < 8; ++ct) {
        const int col = ct * 16 + l15;
        const int sw  = (col & 7) ^ ((col >> 3) & 7);
        #pragma unroll
        for (int kb = 0; kb < 4; ++kb) {
            const int chunk = col * 16 + kb * 4 + q;
            const int cs = chunk ^ sw;
            const f16x8 bfr = *(const f16x8*)(&Bl[cs * 8]);
            acc[ct] = __builtin_amdgcn_mfma_f32_16x16x32_f16(a[kb], bfr, acc[ct], 0, 0, 0);
        }
    }

    _Float16* outb = isEdge ? msg_h : rootp_h;
    #pragma unroll
    for (int j = 0; j < 4; ++j) {
        const int r = w * 16 + q * 4 + j;
        const int oid = smeta[64 + r];
        if (oid >= 0) {
            #pragma unroll
            for (int ct = 0; ct < 8; ++ct) {
                outb[((size_t)oid << 7) + ct * 16 + l15] = (_Float16)acc[ct][j];
            }
        }
    }
}

// ---------------- kernel 2: finalize, wave-per-graph (verified R8/R12) ----------------
__global__ __launch_bounds__(256) void finalize_kernel(
    const _Float16* __restrict__ rootp_h, const _Float16* __restrict__ msg_h,
    const float* __restrict__ bias, const float* __restrict__ target,
    const int* __restrict__ edge_index, float* __restrict__ out)
{
    const int g = blockIdx.x * 4 + (threadIdx.x >> 6);
    const int l = threadIdx.x & 63;
    const int d0 = l * 2;

    const float2 bv = *(const float2*)(bias + d0);
    float accA[NPG], accB[NPG];
    #pragma unroll
    for (int n = 0; n < NPG; ++n) {
        const _Float16* row = rootp_h + ((size_t)(g * NPG + n) << 7) + d0;
        accA[n] = bv.x + (float)row[0];
        accB[n] = bv.y + (float)row[1];
    }

    const int ebase = g * EPG;
    #pragma unroll
    for (int e = 0; e < EPG; ++e) {
        const int ge  = ebase + e;
        const int dst = edge_index[NUM_EDGES + ge] - g * NPG;
        const _Float16* mrow = msg_h + ((size_t)ge << 7) + d0;
        const float m0 = (float)mrow[0];
        const float m1 = (float)mrow[1];
        #pragma unroll
        for (int n = 0; n < NPG; ++n) {
            accA[n] += (n == dst) ? m0 : 0.f;
            accB[n] += (n == dst) ? m1 : 0.f;
        }
    }

    float p0 = 0.f, p1 = 0.f;
    #pragma unroll
    for (int n = 0; n < NPG; ++n) {
        p0 += fmaxf(accA[n], 0.f);
        p1 += fmaxf(accB[n], 0.f);
    }

    const float2 tv = *(const float2*)(target + (size_t)g * DIM + d0);
    float num_p = p0 * tv.x + p1 * tv.y;
    float na_p  = p0 * p0 + p1 * p1;
    float nb_p  = tv.x * tv.x + tv.y * tv.y;

    #pragma unroll
    for (int off = 32; off > 0; off >>= 1) {
        num_p += __shfl_down(num_p, off);
        na_p  += __shfl_down(na_p, off);
        nb_p  += __shfl_down(nb_p, off);
    }
    if (l == 0) {
        const float na = fmaxf(sqrtf(na_p), EPS);
        const float nb = fmaxf(sqrtf(nb_p), EPS);
        out[g] = num_p / (na * nb);
    }
}

// ---------------- fallback: verified fp32 single-kernel version (52.8 us) ----------------
__global__ __launch_bounds__(128) void rgcn_fused_kernel(
    const float* __restrict__ x, const float* __restrict__ basis,
    const float* __restrict__ root, const float* __restrict__ bias,
    const float* __restrict__ target, const int* __restrict__ edge_index,
    const int* __restrict__ edge_type, float* __restrict__ out)
{
    const int g = blockIdx.x;
    const int o = threadIdx.x;
    __shared__ float xs[NPG][DIM];
    __shared__ float red[6];
    {
        const float4* xg = reinterpret_cast<const float4*>(x + (size_t)g * NPG * DIM);
        float4* xs4 = reinterpret_cast<float4*>(&xs[0][0]);
        xs4[o] = xg[o];
        xs4[o + 128] = xg[o + 128];
    }
    __syncthreads();
    float acc[NPG];
    const float b = bias[o];
    #pragma unroll
    for (int n = 0; n < NPG; ++n) acc[n] = b;
    for (int d4 = 0; d4 < DIM / 4; ++d4) {
        const float r0 = root[(d4 * 4 + 0) * DIM + o];
        const float r1 = root[(d4 * 4 + 1) * DIM + o];
        const float r2 = root[(d4 * 4 + 2) * DIM + o];
        const float r3 = root[(d4 * 4 + 3) * DIM + o];
        #pragma unroll
        for (int n = 0; n < NPG; ++n) {
            const float4 xv = reinterpret_cast<const float4*>(&xs[n][0])[d4];
            acc[n] += xv.x * r0 + xv.y * r1 + xv.z * r2 + xv.w * r3;
        }
    }
    const int ebase = g * EPG;
    for (int e = 0; e < EPG; ++e) {
        const int ge  = ebase + e;
        const int src = edge_index[ge] - g * NPG;
        const int dst = edge_index[NUM_EDGES + ge] - g * NPG;
        const int rel = edge_type[ge];
        const float* __restrict__ B = basis + (size_t)rel * DIM * DIM;
        float m = 0.f;
        for (int d4 = 0; d4 < DIM / 4; ++d4) {
            const float4 xv = reinterpret_cast<const float4*>(&xs[src][0])[d4];
            m += xv.x * B[(d4 * 4 + 0) * DIM + o];
            m += xv.y * B[(d4 * 4 + 1) * DIM + o];
            m += xv.z * B[(d4 * 4 + 2) * DIM + o];
            m += xv.w * B[(d4 * 4 + 3) * DIM + o];
        }
        #pragma unroll
        for (int n = 0; n < NPG; ++n) acc[n] += (n == dst) ? m : 0.f;
    }
    float p = 0.f;
    #pragma unroll
    for (int n = 0; n < NPG; ++n) p += fmaxf(acc[n], 0.f);
    const float t = target[(size_t)g * DIM + o];
    float num_p = p * t, na_p = p * p, nb_p = t * t;
    #pragma unroll
    for (int off = 32; off > 0; off >>= 1) {
        num_p += __shfl_down(num_p, off);
        na_p  += __shfl_down(na_p, off);
        nb_p  += __shfl_down(nb_p, off);
    }
    const int wave = o >> 6, lane = o & 63;
    if (lane == 0) {
        red[wave * 3 + 0] = num_p;
        red[wave * 3 + 1] = na_p;
        red[wave * 3 + 2] = nb_p;
    }
    __syncthreads();
    if (o == 0) {
        const float num = red[0] + red[3];
        const float na  = fmaxf(sqrtf(red[1] + red[4]), EPS);
        const float nb  = fmaxf(sqrtf(red[2] + red[5]), EPS);
        out[g] = num / (na * nb);
    }
}

extern "C" void kernel_launch(void* const* d_in, const int* in_sizes, int n_in,
                              void* d_out, int out_size, void* d_ws, size_t ws_size,
                              hipStream_t stream) {
    const float* x          = (const float*)d_in[0];
    const float* basis      = (const float*)d_in[1];
    const float* root       = (const float*)d_in[2];
    const float* bias       = (const float*)d_in[3];
    const float* target     = (const float*)d_in[4];
    const int*   edge_index = (const int*)d_in[5];
    const int*   edge_type  = (const int*)d_in[6];
    float* out = (float*)d_out;

    if (ws_size < WS_NEEDED) {
        rgcn_fused_kernel<<<BATCH, 128, 0, stream>>>(
            x, basis, root, bias, target, edge_index, edge_type, out);
        return;
    }

    char* ws = (char*)d_ws;
    _Float16* msg_h   = (_Float16*)(ws + MSG_OFF);
    _Float16* rootp_h = (_Float16*)(ws + RTP_OFF);

    gemm2_kernel<<<EDGE_BLOCKS + ROOT_BLOCKS, 256, 0, stream>>>(
        x, basis, root, edge_index, edge_type, msg_h, rootp_h);
    finalize_kernel<<<BATCH / 4, 256, 0, stream>>>(
        rootp_h, msg_h, bias, target, edge_index, out);
}

// Round 14
// 22.250 us; speedup vs baseline: 10.3334x; 1.0498x over previous
//
#include <hip/hip_runtime.h>

#define NUM_NODES 16384
#define NPG 8
#define NUM_EDGES 14336
#define EPG 7
#define NUM_RELS 64
#define DIM 128
#define BATCH 2048
#define EPS 1e-8f

#define SEG 1792                     // NUM_EDGES / 8 segments
#define ROOT_BLOCKS 256              // 16384 / 64, dispatched FIRST (uniform tail)
#define EDGE_BLOCKS 512              // 64 rel x 8 segments, <=64 edges each (avg 28, +6.9 sigma to cap)

using f16x8 = __attribute__((ext_vector_type(8))) _Float16;
using f32x4 = __attribute__((ext_vector_type(4))) float;

// ---- ws layout (bytes) ----
#define MSG_OFF 0u                   // msg_h: 14336*128*2 = 3670016
#define RTP_OFF 3670016u             // rootp: 16384*128*2 = 4194304
#define WS_NEEDED 7864320u

// ---------------- kernel 1: fused bucket + pack + MFMA GEMM ----------------
// Root block (bid<256): rows bid*64..+63 with root matrix.
// Edge block (rel=(bid-256)>>3, part=(bid-256)&7): bucket its own 1792-edge
// segment via LDS-atomic slot grab (slot order irrelevant: msg rows are keyed
// by absolute edge id -> output deterministic), pack B[rel] fp32->f16
// transposed into LDS, 64-row MFMA strip. Scan and pack interleave; only 2
// barriers total (R13 had 14 serial scan barriers on the critical path).
// LDS: 16B chunks, chunk = col*16+k16, swizzle cs = chunk^(col&7)^((col>>3)&7)
// -> conflict-free on both transpose stores and fragment reads.
__global__ __launch_bounds__(256) void gemm2_kernel(
    const float* __restrict__ x, const float* __restrict__ basis,
    const float* __restrict__ root, const int* __restrict__ edge_index,
    const int* __restrict__ edge_type,
    _Float16* __restrict__ msg_h, _Float16* __restrict__ rootp_h)
{
    __shared__ _Float16 Bl[DIM * DIM];   // 32 KB
    __shared__ int smeta[128];           // [0:64) src node, [64:128) out row id (-1 = skip)
    __shared__ int lcnt;

    const int bid = blockIdx.x;
    const int tid = threadIdx.x;
    const int lane = tid & 63;
    const int w    = tid >> 6;
    const bool isEdge = bid >= ROOT_BLOCKS;

    const float* Bsrc;

    // ---- init LDS metadata ----
    if (isEdge) {
        if (tid < 64) { smeta[tid] = 0; smeta[64 + tid] = -1; }
        if (tid == 0) lcnt = 0;
        Bsrc = basis + ((size_t)((bid - ROOT_BLOCKS) >> 3) << 14);
    } else {
        const int row0 = bid * 64;
        if (tid < 64) {
            smeta[tid] = row0 + tid;
            smeta[64 + tid] = row0 + tid;
        }
        Bsrc = root;
    }
    __syncthreads();

    // ---- scan (edge blocks only; no barriers) ----
    if (isEdge) {
        const int eb   = bid - ROOT_BLOCKS;
        const int rel  = eb >> 3;
        const int seg0 = (eb & 7) * SEG;
        #pragma unroll
        for (int it = 0; it < 7; ++it) {
            const int e = seg0 + it * 256 + tid;
            if (edge_type[e] == rel) {
                const int pos = atomicAdd(&lcnt, 1);
                if (pos < 64) {
                    smeta[pos] = edge_index[e];      // global src node
                    smeta[64 + pos] = e;             // msg row id
                }
            }
        }
    }

    // ---- pack B: fp32 [d][o] -> LDS f16 [col][k], 8x8 in-register transpose ----
    // (independent of scan; interleaves with it)
    {
        const int br = tid >> 4;         // d-block (k16 = br)
        const int bc = tid & 15;         // o-block
        const float* src = Bsrc + (br * 8) * DIM + bc * 8;
        _Float16 m[8][8];
        #pragma unroll
        for (int u = 0; u < 8; ++u) {
            const float4 a = *(const float4*)(src + u * DIM);
            const float4 b = *(const float4*)(src + u * DIM + 4);
            m[u][0] = (_Float16)a.x; m[u][1] = (_Float16)a.y;
            m[u][2] = (_Float16)a.z; m[u][3] = (_Float16)a.w;
            m[u][4] = (_Float16)b.x; m[u][5] = (_Float16)b.y;
            m[u][6] = (_Float16)b.z; m[u][7] = (_Float16)b.w;
        }
        #pragma unroll
        for (int c2 = 0; c2 < 8; ++c2) {
            const int col = bc * 8 + c2;
            const int chunk = col * 16 + br;
            const int cs = chunk ^ (c2 & 7) ^ (bc & 7);   // == chunk^(col&7)^((col>>3)&7)
            f16x8 v = {m[0][c2], m[1][c2], m[2][c2], m[3][c2],
                       m[4][c2], m[5][c2], m[6][c2], m[7][c2]};
            *(f16x8*)(&Bl[cs * 8]) = v;
        }
    }
    __syncthreads();

    if (isEdge && lcnt == 0) return;     // block-uniform (P ~ e^-28, safety only)

    const int l15 = lane & 15;
    const int q   = lane >> 4;

    // A fragments: gather fp32 x row, convert in-register (verified R9-R13)
    const int src = smeta[w * 16 + l15];
    const float* xrow = x + ((size_t)src << 7) + q * 8;
    f16x8 a[4];
    #pragma unroll
    for (int kb = 0; kb < 4; ++kb) {
        const float4 lo = *(const float4*)(xrow + kb * 32);
        const float4 hi = *(const float4*)(xrow + kb * 32 + 4);
        f16x8 av;
        av[0] = (_Float16)lo.x; av[1] = (_Float16)lo.y;
        av[2] = (_Float16)lo.z; av[3] = (_Float16)lo.w;
        av[4] = (_Float16)hi.x; av[5] = (_Float16)hi.y;
        av[6] = (_Float16)hi.z; av[7] = (_Float16)hi.w;
        a[kb] = av;
    }

    f32x4 acc[8];
    #pragma unroll
    for (int ct = 0; ct < 8; ++ct) acc[ct] = (f32x4){0.f, 0.f, 0.f, 0.f};

    #pragma unroll
    for (int ct = 0; ct < 8; ++ct) {
        const int col = ct * 16 + l15;
        const int sw  = (col & 7) ^ ((col >> 3) & 7);
        #pragma unroll
        for (int kb = 0; kb < 4; ++kb) {
            const int chunk = col * 16 + kb * 4 + q;
            const int cs = chunk ^ sw;
            const f16x8 bfr = *(const f16x8*)(&Bl[cs * 8]);
            acc[ct] = __builtin_amdgcn_mfma_f32_16x16x32_f16(a[kb], bfr, acc[ct], 0, 0, 0);
        }
    }

    _Float16* outb = isEdge ? msg_h : rootp_h;
    #pragma unroll
    for (int j = 0; j < 4; ++j) {
        const int r = w * 16 + q * 4 + j;
        const int oid = smeta[64 + r];
        if (oid >= 0) {
            #pragma unroll
            for (int ct = 0; ct < 8; ++ct) {
                outb[((size_t)oid << 7) + ct * 16 + l15] = (_Float16)acc[ct][j];
            }
        }
    }
}

// ---------------- kernel 2: finalize, wave-per-graph (512-thread blocks) ----------------
__global__ __launch_bounds__(512) void finalize_kernel(
    const _Float16* __restrict__ rootp_h, const _Float16* __restrict__ msg_h,
    const float* __restrict__ bias, const float* __restrict__ target,
    const int* __restrict__ edge_index, float* __restrict__ out)
{
    const int g = blockIdx.x * 8 + (threadIdx.x >> 6);
    const int l = threadIdx.x & 63;
    const int d0 = l * 2;

    const float2 bv = *(const float2*)(bias + d0);
    float accA[NPG], accB[NPG];
    #pragma unroll
    for (int n = 0; n < NPG; ++n) {
        const _Float16* row = rootp_h + ((size_t)(g * NPG + n) << 7) + d0;
        accA[n] = bv.x + (float)row[0];
        accB[n] = bv.y + (float)row[1];
    }

    const int ebase = g * EPG;
    #pragma unroll
    for (int e = 0; e < EPG; ++e) {
        const int ge  = ebase + e;
        const int dst = edge_index[NUM_EDGES + ge] - g * NPG;
        const _Float16* mrow = msg_h + ((size_t)ge << 7) + d0;
        const float m0 = (float)mrow[0];
        const float m1 = (float)mrow[1];
        #pragma unroll
        for (int n = 0; n < NPG; ++n) {
            accA[n] += (n == dst) ? m0 : 0.f;
            accB[n] += (n == dst) ? m1 : 0.f;
        }
    }

    float p0 = 0.f, p1 = 0.f;
    #pragma unroll
    for (int n = 0; n < NPG; ++n) {
        p0 += fmaxf(accA[n], 0.f);
        p1 += fmaxf(accB[n], 0.f);
    }

    const float2 tv = *(const float2*)(target + (size_t)g * DIM + d0);
    float num_p = p0 * tv.x + p1 * tv.y;
    float na_p  = p0 * p0 + p1 * p1;
    float nb_p  = tv.x * tv.x + tv.y * tv.y;

    #pragma unroll
    for (int off = 32; off > 0; off >>= 1) {
        num_p += __shfl_down(num_p, off);
        na_p  += __shfl_down(na_p, off);
        nb_p  += __shfl_down(nb_p, off);
    }
    if (l == 0) {
        const float na = fmaxf(sqrtf(na_p), EPS);
        const float nb = fmaxf(sqrtf(nb_p), EPS);
        out[g] = num_p / (na * nb);
    }
}

// ---------------- fallback: verified fp32 single-kernel version (52.8 us) ----------------
__global__ __launch_bounds__(128) void rgcn_fused_kernel(
    const float* __restrict__ x, const float* __restrict__ basis,
    const float* __restrict__ root, const float* __restrict__ bias,
    const float* __restrict__ target, const int* __restrict__ edge_index,
    const int* __restrict__ edge_type, float* __restrict__ out)
{
    const int g = blockIdx.x;
    const int o = threadIdx.x;
    __shared__ float xs[NPG][DIM];
    __shared__ float red[6];
    {
        const float4* xg = reinterpret_cast<const float4*>(x + (size_t)g * NPG * DIM);
        float4* xs4 = reinterpret_cast<float4*>(&xs[0][0]);
        xs4[o] = xg[o];
        xs4[o + 128] = xg[o + 128];
    }
    __syncthreads();
    float acc[NPG];
    const float b = bias[o];
    #pragma unroll
    for (int n = 0; n < NPG; ++n) acc[n] = b;
    for (int d4 = 0; d4 < DIM / 4; ++d4) {
        const float r0 = root[(d4 * 4 + 0) * DIM + o];
        const float r1 = root[(d4 * 4 + 1) * DIM + o];
        const float r2 = root[(d4 * 4 + 2) * DIM + o];
        const float r3 = root[(d4 * 4 + 3) * DIM + o];
        #pragma unroll
        for (int n = 0; n < NPG; ++n) {
            const float4 xv = reinterpret_cast<const float4*>(&xs[n][0])[d4];
            acc[n] += xv.x * r0 + xv.y * r1 + xv.z * r2 + xv.w * r3;
        }
    }
    const int ebase = g * EPG;
    for (int e = 0; e < EPG; ++e) {
        const int ge  = ebase + e;
        const int src = edge_index[ge] - g * NPG;
        const int dst = edge_index[NUM_EDGES + ge] - g * NPG;
        const int rel = edge_type[ge];
        const float* __restrict__ B = basis + (size_t)rel * DIM * DIM;
        float m = 0.f;
        for (int d4 = 0; d4 < DIM / 4; ++d4) {
            const float4 xv = reinterpret_cast<const float4*>(&xs[src][0])[d4];
            m += xv.x * B[(d4 * 4 + 0) * DIM + o];
            m += xv.y * B[(d4 * 4 + 1) * DIM + o];
            m += xv.z * B[(d4 * 4 + 2) * DIM + o];
            m += xv.w * B[(d4 * 4 + 3) * DIM + o];
        }
        #pragma unroll
        for (int n = 0; n < NPG; ++n) acc[n] += (n == dst) ? m : 0.f;
    }
    float p = 0.f;
    #pragma unroll
    for (int n = 0; n < NPG; ++n) p += fmaxf(acc[n], 0.f);
    const float t = target[(size_t)g * DIM + o];
    float num_p = p * t, na_p = p * p, nb_p = t * t;
    #pragma unroll
    for (int off = 32; off > 0; off >>= 1) {
        num_p += __shfl_down(num_p, off);
        na_p  += __shfl_down(na_p, off);
        nb_p  += __shfl_down(nb_p, off);
    }
    const int wave = o >> 6, lane = o & 63;
    if (lane == 0) {
        red[wave * 3 + 0] = num_p;
        red[wave * 3 + 1] = na_p;
        red[wave * 3 + 2] = nb_p;
    }
    __syncthreads();
    if (o == 0) {
        const float num = red[0] + red[3];
        const float na  = fmaxf(sqrtf(red[1] + red[4]), EPS);
        const float nb  = fmaxf(sqrtf(red[2] + red[5]), EPS);
        out[g] = num / (na * nb);
    }
}

extern "C" void kernel_launch(void* const* d_in, const int* in_sizes, int n_in,
                              void* d_out, int out_size, void* d_ws, size_t ws_size,
                              hipStream_t stream) {
    const float* x          = (const float*)d_in[0];
    const float* basis      = (const float*)d_in[1];
    const float* root       = (const float*)d_in[2];
    const float* bias       = (const float*)d_in[3];
    const float* target     = (const float*)d_in[4];
    const int*   edge_index = (const int*)d_in[5];
    const int*   edge_type  = (const int*)d_in[6];
    float* out = (float*)d_out;

    if (ws_size < WS_NEEDED) {
        rgcn_fused_kernel<<<BATCH, 128, 0, stream>>>(
            x, basis, root, bias, target, edge_index, edge_type, out);
        return;
    }

    char* ws = (char*)d_ws;
    _Float16* msg_h   = (_Float16*)(ws + MSG_OFF);
    _Float16* rootp_h = (_Float16*)(ws + RTP_OFF);

    gemm2_kernel<<<ROOT_BLOCKS + EDGE_BLOCKS, 256, 0, stream>>>(
        x, basis, root, edge_index, edge_type, msg_h, rootp_h);
    finalize_kernel<<<BATCH / 8, 512, 0, stream>>>(
        rootp_h, msg_h, bias, target, edge_index, out);
}